// Round 1
// baseline (54610.687 us; speedup 1.0000x reference)
//
#include <hip/hip_runtime.h>
#include <hip/hip_bf16.h>

#define BB 32
#define TT 512
#define VV 4096
#define HH 1024

// ---------------------------------------------------------------------------
// Transpose w_ih_0 [4H, V] -> wT [V, 4H] so per-step one-hot gathers are
// row-contiguous.
// ---------------------------------------------------------------------------
__global__ __launch_bounds__(256) void transpose_kernel(
    const float* __restrict__ in, float* __restrict__ out)
{
    __shared__ float tile[32][33];
    const int bx = blockIdx.x;  // V/32 column tiles (of input)
    const int by = blockIdx.y;  // 4H/32 row tiles (of input)
    const int txi = threadIdx.x;  // 0..31
    const int tyi = threadIdx.y;  // 0..7
    const int x = bx * 32 + txi;          // column in input (v)
    #pragma unroll
    for (int i = 0; i < 32; i += 8) {
        int y = by * 32 + tyi + i;        // row in input (g)
        tile[tyi + i][txi] = in[(size_t)y * VV + x];
    }
    __syncthreads();
    #pragma unroll
    for (int i = 0; i < 32; i += 8) {
        int vrow = bx * 32 + tyi + i;     // row in output (v)
        int gcol = by * 32 + txi;         // col in output (g)
        out[(size_t)vrow * (4 * HH) + gcol] = tile[txi][tyi + i];
    }
}

// ---------------------------------------------------------------------------
// LSTM layer 0, one time step. Grid 256 WGs x 512 threads.
// WG wg owns h-indices j in [4wg, 4wg+4) -> 16 gate rows (i,f,g,o x 4).
// Thread: bq = tid&7 (4 batches), rp = (tid>>3)&7 (2 gate rows), ks = tid>>6
// (K-split 8 x 128). LDS reduction over ks, then 128 threads do activations.
// ---------------------------------------------------------------------------
__global__ __launch_bounds__(512) void lstm0_step(
    int t, const int* __restrict__ x, const float* __restrict__ wT,
    const float* __restrict__ w_hh, const float* __restrict__ b_ih,
    const float* __restrict__ b_hh, const float* __restrict__ hid,
    const float* __restrict__ mem, float* __restrict__ out0,
    float* __restrict__ c_ws)
{
    const int wg = blockIdx.x;
    const int tid = threadIdx.x;
    const int bq = tid & 7;
    const int rp = (tid >> 3) & 7;
    const int ks = tid >> 6;

    const float* hprev = (t == 0) ? hid : (out0 + (size_t)(t - 1) * (BB * HH));

    const int gl0 = 2 * rp, gl1 = gl0 + 1;
    const int row0 = (gl0 >> 2) * HH + 4 * wg + (gl0 & 3);
    const int row1 = (gl1 >> 2) * HH + 4 * wg + (gl1 & 3);
    const float* w0 = w_hh + (size_t)row0 * HH + ks * 128;
    const float* w1 = w_hh + (size_t)row1 * HH + ks * 128;
    const float* hb = hprev + (size_t)(4 * bq) * HH + ks * 128;

    float acc[4][2] = {};
    #pragma unroll 4
    for (int k = 0; k < 128; k += 4) {
        float4 a = *(const float4*)(w0 + k);
        float4 c = *(const float4*)(w1 + k);
        #pragma unroll
        for (int m = 0; m < 4; ++m) {
            float4 h4 = *(const float4*)(hb + (size_t)m * HH + k);
            acc[m][0] += h4.x * a.x + h4.y * a.y + h4.z * a.z + h4.w * a.w;
            acc[m][1] += h4.x * c.x + h4.y * c.y + h4.z * c.z + h4.w * c.w;
        }
    }

    __shared__ float part[8][16][32];
    #pragma unroll
    for (int m = 0; m < 4; ++m) {
        part[ks][gl0][4 * bq + m] = acc[m][0];
        part[ks][gl1][4 * bq + m] = acc[m][1];
    }
    __syncthreads();

    if (tid < 128) {
        const int b = tid & 31, jj = tid >> 5;
        const int j = 4 * wg + jj;
        const int tok = x[(size_t)b * TT + t];
        float g4[4];
        #pragma unroll
        for (int gt = 0; gt < 4; ++gt) {
            const int gl = gt * 4 + jj;
            float s = 0.f;
            #pragma unroll
            for (int q = 0; q < 8; ++q) s += part[q][gl][b];
            const int grow = gt * HH + j;
            s += b_ih[grow] + b_hh[grow] + wT[(size_t)tok * (4 * HH) + grow];
            g4[gt] = s;
        }
        const float ig = 1.f / (1.f + __expf(-g4[0]));
        const float fg = 1.f / (1.f + __expf(-g4[1]));
        const float gg = 2.f / (1.f + __expf(-2.f * g4[2])) - 1.f;
        const float og = 1.f / (1.f + __expf(-g4[3]));
        const float cold = (t == 0) ? mem[b * HH + j] : c_ws[b * HH + j];
        const float cn = fg * cold + ig * gg;
        const float hn = og * (2.f / (1.f + __expf(-2.f * cn)) - 1.f);
        c_ws[b * HH + j] = cn;
        out0[(size_t)t * (BB * HH) + b * HH + j] = hn;
    }
}

// ---------------------------------------------------------------------------
// LSTM layer 1, one time step. Same structure, but gates =
// out0[t] @ w_ih_1^T + h1_prev @ w_hh_1^T + biases (fused K=2048).
// ---------------------------------------------------------------------------
__global__ __launch_bounds__(512) void lstm1_step(
    int t, const float* __restrict__ out0, const float* __restrict__ w_ih,
    const float* __restrict__ w_hh, const float* __restrict__ b_ih,
    const float* __restrict__ b_hh, const float* __restrict__ hid,
    const float* __restrict__ mem, float* __restrict__ out1,
    float* __restrict__ c_ws)
{
    const int wg = blockIdx.x;
    const int tid = threadIdx.x;
    const int bq = tid & 7;
    const int rp = (tid >> 3) & 7;
    const int ks = tid >> 6;

    const float* xrow = out0 + (size_t)t * (BB * HH);
    const float* hprev = (t == 0) ? hid : (out1 + (size_t)(t - 1) * (BB * HH));

    const int gl0 = 2 * rp, gl1 = gl0 + 1;
    const int row0 = (gl0 >> 2) * HH + 4 * wg + (gl0 & 3);
    const int row1 = (gl1 >> 2) * HH + 4 * wg + (gl1 & 3);
    const float* wi0 = w_ih + (size_t)row0 * HH + ks * 128;
    const float* wi1 = w_ih + (size_t)row1 * HH + ks * 128;
    const float* wh0 = w_hh + (size_t)row0 * HH + ks * 128;
    const float* wh1 = w_hh + (size_t)row1 * HH + ks * 128;
    const float* xb = xrow + (size_t)(4 * bq) * HH + ks * 128;
    const float* hb = hprev + (size_t)(4 * bq) * HH + ks * 128;

    float acc[4][2] = {};
    #pragma unroll 2
    for (int k = 0; k < 128; k += 4) {
        float4 a = *(const float4*)(wi0 + k);
        float4 c = *(const float4*)(wi1 + k);
        float4 d = *(const float4*)(wh0 + k);
        float4 e = *(const float4*)(wh1 + k);
        #pragma unroll
        for (int m = 0; m < 4; ++m) {
            float4 x4 = *(const float4*)(xb + (size_t)m * HH + k);
            float4 h4 = *(const float4*)(hb + (size_t)m * HH + k);
            acc[m][0] += x4.x * a.x + x4.y * a.y + x4.z * a.z + x4.w * a.w
                       + h4.x * d.x + h4.y * d.y + h4.z * d.z + h4.w * d.w;
            acc[m][1] += x4.x * c.x + x4.y * c.y + x4.z * c.z + x4.w * c.w
                       + h4.x * e.x + h4.y * e.y + h4.z * e.z + h4.w * e.w;
        }
    }

    __shared__ float part[8][16][32];
    #pragma unroll
    for (int m = 0; m < 4; ++m) {
        part[ks][gl0][4 * bq + m] = acc[m][0];
        part[ks][gl1][4 * bq + m] = acc[m][1];
    }
    __syncthreads();

    if (tid < 128) {
        const int b = tid & 31, jj = tid >> 5;
        const int j = 4 * wg + jj;
        float g4[4];
        #pragma unroll
        for (int gt = 0; gt < 4; ++gt) {
            const int gl = gt * 4 + jj;
            float s = 0.f;
            #pragma unroll
            for (int q = 0; q < 8; ++q) s += part[q][gl][b];
            const int grow = gt * HH + j;
            s += b_ih[grow] + b_hh[grow];
            g4[gt] = s;
        }
        const float ig = 1.f / (1.f + __expf(-g4[0]));
        const float fg = 1.f / (1.f + __expf(-g4[1]));
        const float gg = 2.f / (1.f + __expf(-2.f * g4[2])) - 1.f;
        const float og = 1.f / (1.f + __expf(-g4[3]));
        const float cold = (t == 0) ? mem[b * HH + j] : c_ws[b * HH + j];
        const float cn = fg * cold + ig * gg;
        const float hn = og * (2.f / (1.f + __expf(-2.f * cn)) - 1.f);
        c_ws[b * HH + j] = cn;
        out1[(size_t)t * (BB * HH) + b * HH + j] = hn;
    }
}

// ---------------------------------------------------------------------------
// Final FC: logits[b,t,v] = out1[t,b,:] . fc_w[v,:] + fc_b[v]
// A = out1 as [M=T*B, K=H] (row r = t*B + b), B = fc_w [V, H].
// 128x128 tile, BK=16, 8x8 micro-tile per thread.
// ---------------------------------------------------------------------------
__global__ __launch_bounds__(256) void fc_gemm(
    const float* __restrict__ A, const float* __restrict__ Bw,
    const float* __restrict__ bias, float* __restrict__ outp)
{
    __shared__ float As[16][132];
    __shared__ float Bs[16][132];
    const int bm = blockIdx.x;  // 128 M-tiles
    const int bn = blockIdx.y;  // 32 N-tiles
    const int tid = threadIdx.x;
    const int tx = tid & 15, ty = tid >> 4;

    float acc[8][8] = {};
    const float* Abase = A + (size_t)bm * 128 * HH;
    const float* Bbase = Bw + (size_t)bn * 128 * HH;

    for (int k0 = 0; k0 < HH; k0 += 16) {
        #pragma unroll
        for (int c = 0; c < 2; ++c) {
            const int idx = tid + c * 256;     // 0..511
            const int r = idx >> 2;            // 0..127
            const int kq = (idx & 3) * 4;      // 0,4,8,12
            float4 av = *(const float4*)(Abase + (size_t)r * HH + k0 + kq);
            float4 bv = *(const float4*)(Bbase + (size_t)r * HH + k0 + kq);
            As[kq + 0][r] = av.x; As[kq + 1][r] = av.y;
            As[kq + 2][r] = av.z; As[kq + 3][r] = av.w;
            Bs[kq + 0][r] = bv.x; Bs[kq + 1][r] = bv.y;
            Bs[kq + 2][r] = bv.z; Bs[kq + 3][r] = bv.w;
        }
        __syncthreads();
        #pragma unroll
        for (int k = 0; k < 16; ++k) {
            float a[8], b[8];
            *(float4*)&a[0] = *(const float4*)&As[k][ty * 8];
            *(float4*)&a[4] = *(const float4*)&As[k][ty * 8 + 4];
            *(float4*)&b[0] = *(const float4*)&Bs[k][tx * 8];
            *(float4*)&b[4] = *(const float4*)&Bs[k][tx * 8 + 4];
            #pragma unroll
            for (int i = 0; i < 8; ++i)
                #pragma unroll
                for (int j = 0; j < 8; ++j)
                    acc[i][j] += a[i] * b[j];
        }
        __syncthreads();
    }

    const int vbase = bn * 128 + tx * 8;
    #pragma unroll
    for (int i = 0; i < 8; ++i) {
        const int r = bm * 128 + ty * 8 + i;
        const int b = r & 31;
        const int t = r >> 5;
        float* dst = outp + ((size_t)b * TT + t) * VV + vbase;
        float4 o0, o1;
        o0.x = acc[i][0] + bias[vbase + 0];
        o0.y = acc[i][1] + bias[vbase + 1];
        o0.z = acc[i][2] + bias[vbase + 2];
        o0.w = acc[i][3] + bias[vbase + 3];
        o1.x = acc[i][4] + bias[vbase + 4];
        o1.y = acc[i][5] + bias[vbase + 5];
        o1.z = acc[i][6] + bias[vbase + 6];
        o1.w = acc[i][7] + bias[vbase + 7];
        *(float4*)dst = o0;
        *(float4*)(dst + 4) = o1;
    }
}

// ---------------------------------------------------------------------------
// Copy final h/c states into d_out tail: [logits | h(2,B,H) | c(2,B,H)]
// ---------------------------------------------------------------------------
__global__ __launch_bounds__(256) void finalize(
    const float* __restrict__ out0, const float* __restrict__ out1,
    const float* __restrict__ c0, const float* __restrict__ c1,
    float* __restrict__ dout)
{
    const size_t LOGITS = (size_t)BB * TT * VV;
    const int i = blockIdx.x * 256 + threadIdx.x;  // 0..65535
    const int l = i >> 15;
    const int bh = i & 32767;
    const float* hsrc = l ? out1 : out0;
    const float* csrc = l ? c1 : c0;
    dout[LOGITS + i] = hsrc[(size_t)(TT - 1) * (BB * HH) + bh];
    dout[LOGITS + 65536 + i] = csrc[bh];
}

extern "C" void kernel_launch(void* const* d_in, const int* in_sizes, int n_in,
                              void* d_out, int out_size, void* d_ws, size_t ws_size,
                              hipStream_t stream)
{
    const int* x = (const int*)d_in[0];
    const float* hidden = (const float*)d_in[1];
    const float* memory = (const float*)d_in[2];
    const float* w_ih_0 = (const float*)d_in[3];
    const float* w_hh_0 = (const float*)d_in[4];
    const float* b_ih_0 = (const float*)d_in[5];
    const float* b_hh_0 = (const float*)d_in[6];
    const float* w_ih_1 = (const float*)d_in[7];
    const float* w_hh_1 = (const float*)d_in[8];
    const float* b_ih_1 = (const float*)d_in[9];
    const float* b_hh_1 = (const float*)d_in[10];
    const float* fc_w = (const float*)d_in[11];
    const float* fc_b = (const float*)d_in[12];
    float* outp = (float*)d_out;

    float* ws = (float*)d_ws;
    float* wT = ws;                                   // 4096*4096
    float* out0 = wT + (size_t)VV * (4 * HH);         // T*B*H
    float* out1 = out0 + (size_t)TT * BB * HH;        // T*B*H
    float* c0 = out1 + (size_t)TT * BB * HH;          // B*H
    float* c1 = c0 + (size_t)BB * HH;                 // B*H

    transpose_kernel<<<dim3(VV / 32, (4 * HH) / 32), dim3(32, 8), 0, stream>>>(
        w_ih_0, wT);

    for (int t = 0; t < TT; ++t)
        lstm0_step<<<256, 512, 0, stream>>>(t, x, wT, w_hh_0, b_ih_0, b_hh_0,
                                            hidden, memory, out0, c0);

    for (int t = 0; t < TT; ++t)
        lstm1_step<<<256, 512, 0, stream>>>(t, out0, w_ih_1, w_hh_1, b_ih_1,
                                            b_hh_1, hidden + BB * HH,
                                            memory + BB * HH, out1, c1);

    fc_gemm<<<dim3(128, 32), 256, 0, stream>>>(out1, fc_w, fc_b, outp);

    finalize<<<256, 256, 0, stream>>>(out0, out1, c0, c1, outp);
}